// Round 12
// baseline (975.744 us; speedup 1.0000x reference)
//
#include <hip/hip_runtime.h>
#include <stdint.h>

typedef unsigned short u16;
typedef unsigned int u32;
typedef __attribute__((ext_vector_type(8))) short short8;   // 8 bf16 (4 VGPR)
typedef __attribute__((ext_vector_type(4))) float f32x4;

#define NTHR 384
#define JOBS 16
#define K2E16 0.09016844005556021f   /* log2(e)/16 : 1/sqrt(256) folded into exp2 */

// LDS map (146304 B, 1 block/CU persistent-job kernel):
//   wkqL  [0,      36864) : Wkq frags, staged ONCE per block, resident
//   wvoD  [36864,  69632) : Wvo 16KB double-buffer (streamed per job)
//   kwL   [69632,  95744) : KW bf16 [96][272B] per job
//   fragL [95744, 144896) : sigma B-frags (16 nt), per job
//   biasL f32[96] @144896, bvoL f32[256] @145280  -> total 146304
#define WVO_OFF   36864
#define KW_OFF    69632
#define KW_STRIDE 272
#define FRAG_OFF  95744
#define BIAS_OFF  144896
#define BVO_OFF   145280
#define LDS_TOTAL 146304

static __device__ __forceinline__ u16 f2bf(float f) {
  union { float f; u32 u; } v; v.f = f;
  u32 r = v.u + 0x7FFFu + ((v.u >> 16) & 1u);   // RNE
  return (u16)(r >> 16);
}

// ---------------------------------------------------------------------------
// K0: weight prep (identical to round-10/11 verified version).
// ---------------------------------------------------------------------------
__global__ __launch_bounds__(256) void k_setup(
    const float* __restrict__ Wq, const float* __restrict__ Wk,
    const float* __restrict__ Wv, const float* __restrict__ Wo,
    const float* __restrict__ bq,
    const float* __restrict__ bv, const float* __restrict__ bo,
    u16* __restrict__ WkqF, u16* __restrict__ WvoF, float* __restrict__ bvo) {
  const int ci = blockIdx.x;   // k-row
  const int co = threadIdx.x;  // col
  float acc = 0.f;
  for (int h = 0; h < 256; ++h) acc += Wv[ci*256 + h] * Wo[h*256 + co];
  const int lanepart = ((ci >> 3) & 3)*16 + (co & 15), e = ci & 7;
  const int idxv = (((ci >> 5)*16 + (co >> 4))*64 + lanepart)*8 + e;
  WvoF[idxv] = f2bf(acc);
  if (ci < 128 && co < 144) {
    float a = 0.f;
    if (co < 128)       { for (int h = 0; h < 256; ++h) a += Wk[ci*256 + h] * Wq[co*256 + h]; }
    else if (co == 128) { for (int h = 0; h < 256; ++h) a += Wk[ci*256 + h] * bq[h]; }
    const int idx = (((ci >> 5)*9 + (co >> 4))*64 + lanepart)*8 + e;
    WkqF[idx] = f2bf(a);
  }
  if (ci == 0) {
    float a2 = 0.f;
    for (int h = 0; h < 256; ++h) a2 += bv[h] * Wo[h*256 + co];
    bvo[co] = a2 + bo[co];
  }
}

// ---------------------------------------------------------------------------
// K2 persistent-job kernel, grid (512), 6 waves, 146304B LDS, 1 block/CU.
// Block blk handles b = blk>>6, n in [n0, n0+16), n0 = (blk&63)*16.
// Cross-job pipeline: next job's sd/se issued during P1, enc ring during P5,
// Wvo chunks 0'/1' at kt=6/7 (table repeats -> uniform (kt+2)&7 schedule).
// ---------------------------------------------------------------------------
__global__ __launch_bounds__(NTHR, 2) void k_attn(
    const float* __restrict__ sdec, const float* __restrict__ senc,
    const float* __restrict__ enc,
    const u16* __restrict__ WkqF, const u16* __restrict__ WvoF,
    const float* __restrict__ bvo, float* __restrict__ out) {
  extern __shared__ char smem[];
  char* wkqL   = smem;
  char* wvoD   = smem + WVO_OFF;
  char* kwL    = smem + KW_OFF;
  char* fragL  = smem + FRAG_OFF;
  float* biasL = (float*)(smem + BIAS_OFF);
  float* bvoL  = (float*)(smem + BVO_OFF);

  const int blk = blockIdx.x;
  const int b = blk >> 6;
  const int n0 = (blk & 63) << 4;
  const int tid = threadIdx.x, wave = tid >> 6, lane = tid & 63;
  const int g = lane >> 4, c15 = lane & 15;
  const int prow = 16*wave + c15;      // this wave's A-fragment row
  const size_t rowbase = (size_t)(b*96 + prow)*1024;

  const f32x4* wv = (const f32x4*)WvoF;   // chunk c = wv + c*1024 (16KB)

  // ---- prologue: issue wkq stage loads, job0 inputs, chunks 0/1 ----
  f32x4 wkq[6];
  #pragma unroll
  for (int i = 0; i < 6; ++i) wkq[i] = ((const f32x4*)WkqF)[tid + 384*i];

  const float* sdp = sdec + (rowbase + n0)*128 + 8*g;
  const float* sep = senc + (rowbase + n0)*128 + 8*g;
  float4 sdv[4][2], sev[4][2];
  #pragma unroll
  for (int kt = 0; kt < 4; ++kt) {
    sev[kt][0] = *(const float4*)(sep + 32*kt);
    sev[kt][1] = *(const float4*)(sep + 32*kt + 4);
    sdv[kt][0] = *(const float4*)(sdp + 32*kt);
    sdv[kt][1] = *(const float4*)(sdp + 32*kt + 4);
  }
  f32x4 pf0[3], pf1[3];
  #pragma unroll
  for (int i = 0; i < 3; ++i) {
    const int idx = tid + 384*i;
    if (idx < 1024) { pf0[i] = wv[idx]; pf1[i] = wv[1024 + idx]; }
  }
  const float* ep = enc + (rowbase + n0)*256 + 8*g;
  float4 evr[4][2];
  #pragma unroll
  for (int kt = 0; kt < 4; ++kt) {
    evr[kt][0] = *(const float4*)(ep + 32*kt);
    evr[kt][1] = *(const float4*)(ep + 32*kt + 4);
  }
  if (tid < 256) bvoL[tid] = bvo[tid];

  // commit wkq -> wkqL (resident for the whole block)
  {
    f32x4* d = (f32x4*)wkqL;
    #pragma unroll
    for (int i = 0; i < 6; ++i) d[tid + 384*i] = wkq[i];
  }
  __syncthreads();   // bar0: wkqL staged
  // commit chunk0 -> buf0 (chunk1 stays in pf1, committed at kt=0 of job 0)
  {
    f32x4* b0 = (f32x4*)wvoD;
    #pragma unroll
    for (int i = 0; i < 3; ++i) {
      const int idx = tid + 384*i;
      if (idx < 1024) b0[idx] = pf0[i];
    }
  }

  // ================= job loop =================
  #pragma unroll 1
  for (int j = 0; j < JOBS; ++j) {
    const int n = n0 + j;
    const int nn = n0 + ((j + 1) & (JOBS - 1));   // next job (wraps, always valid)

    // ---- convert this job's inputs (loads issued a full job ago) ----
    short8 sef[4], sdf[4];
    #pragma unroll
    for (int kt = 0; kt < 4; ++kt) {
      union { u32 u[4]; short8 v; } cv;
      cv.u[0] = (u32)f2bf(sev[kt][0].x) | ((u32)f2bf(sev[kt][0].y) << 16);
      cv.u[1] = (u32)f2bf(sev[kt][0].z) | ((u32)f2bf(sev[kt][0].w) << 16);
      cv.u[2] = (u32)f2bf(sev[kt][1].x) | ((u32)f2bf(sev[kt][1].y) << 16);
      cv.u[3] = (u32)f2bf(sev[kt][1].z) | ((u32)f2bf(sev[kt][1].w) << 16);
      sef[kt] = cv.v;
    }
    #pragma unroll
    for (int kt = 0; kt < 4; ++kt) {
      union { u32 u[4]; short8 v; } cv;
      cv.u[0] = (u32)f2bf(sdv[kt][0].x) | ((u32)f2bf(sdv[kt][0].y) << 16);
      cv.u[1] = (u32)f2bf(sdv[kt][0].z) | ((u32)f2bf(sdv[kt][0].w) << 16);
      cv.u[2] = (u32)f2bf(sdv[kt][1].x) | ((u32)f2bf(sdv[kt][1].y) << 16);
      cv.u[3] = (u32)f2bf(sdv[kt][1].z) | ((u32)f2bf(sdv[kt][1].w) << 16);
      sdf[kt] = cv.v;
    }
    // ---- issue NEXT job's sd/se loads (land during this job's compute) ----
    {
      const float* sdpn = sdec + (rowbase + nn)*128 + 8*g;
      const float* sepn = senc + (rowbase + nn)*128 + 8*g;
      #pragma unroll
      for (int kt = 0; kt < 4; ++kt) {
        sev[kt][0] = *(const float4*)(sepn + 32*kt);
        sev[kt][1] = *(const float4*)(sepn + 32*kt + 4);
        sdv[kt][0] = *(const float4*)(sdpn + 32*kt);
        sdv[kt][1] = *(const float4*)(sdpn + 32*kt + 4);
      }
    }

    // ---- P1: KW rows [16w,16w+16) x 144 = senc_rows @ WkqE (B from wkqL) ----
    {
      f32x4 acc[9];
      #pragma unroll
      for (int nt = 0; nt < 9; ++nt) acc[nt] = (f32x4)0.f;
      #pragma unroll
      for (int kt = 0; kt < 4; ++kt) {
        #pragma unroll
        for (int nt = 0; nt < 9; ++nt) {
          const short8 bf = *(const short8*)(wkqL + ((kt*9 + nt)*64 + lane)*16);
          acc[nt] = __builtin_amdgcn_mfma_f32_16x16x32_bf16(sef[kt], bf, acc[nt], 0, 0, 0);
        }
      }
      #pragma unroll
      for (int nt = 0; nt < 8; ++nt) {
        #pragma unroll
        for (int r = 0; r < 4; ++r)
          *(u16*)(kwL + (16*wave + 4*g + r)*KW_STRIDE + 2*(c15 + 16*nt)) = f2bf(acc[nt][r]);
      }
      if (c15 == 0) {
        #pragma unroll
        for (int r = 0; r < 4; ++r) biasL[16*wave + 4*g + r] = acc[8][r];
      }
    }
    __syncthreads();   // bar1: kwL + biasL ready

    // ---- P2: scoresT = KW[:,0:128] @ sdecT + bias; softmax; af pack ----
    f32x4 sac[6];
    #pragma unroll
    for (int pt = 0; pt < 6; ++pt) sac[pt] = (f32x4)0.f;
    #pragma unroll
    for (int kt = 0; kt < 4; ++kt) {
      #pragma unroll
      for (int pt = 0; pt < 6; ++pt) {
        const short8 kf = *(const short8*)(kwL + (16*pt + c15)*KW_STRIDE + 16*g + 64*kt);
        sac[pt] = __builtin_amdgcn_mfma_f32_16x16x32_bf16(kf, sdf[kt], sac[pt], 0, 0, 0);
      }
    }
    #pragma unroll
    for (int pt = 0; pt < 6; ++pt)
      #pragma unroll
      for (int r = 0; r < 4; ++r)
        sac[pt][r] += biasL[16*pt + 4*g + r];

    float m = sac[0][0];
    #pragma unroll
    for (int pt = 0; pt < 6; ++pt)
      #pragma unroll
      for (int r = 0; r < 4; ++r) m = fmaxf(m, sac[pt][r]);
    m = fmaxf(m, __shfl_xor(m, 16));
    m = fmaxf(m, __shfl_xor(m, 32));
    float s = 0.f;
    #pragma unroll
    for (int pt = 0; pt < 6; ++pt)
      #pragma unroll
      for (int r = 0; r < 4; ++r) {
        const float e = exp2f((sac[pt][r] - m) * K2E16);
        sac[pt][r] = e; s += e;
      }
    s += __shfl_xor(s, 16);
    s += __shfl_xor(s, 32);
    const float rs = 1.f / s;

    short8 af[3];
    #pragma unroll
    for (int kb = 0; kb < 3; ++kb) {
      union { u32 u[4]; short8 v; } cv;
      cv.u[0] = (u32)f2bf(sac[2*kb][0]*rs)   | ((u32)f2bf(sac[2*kb][1]*rs)   << 16);
      cv.u[1] = (u32)f2bf(sac[2*kb][2]*rs)   | ((u32)f2bf(sac[2*kb][3]*rs)   << 16);
      cv.u[2] = (u32)f2bf(sac[2*kb+1][0]*rs) | ((u32)f2bf(sac[2*kb+1][1]*rs) << 16);
      cv.u[3] = (u32)f2bf(sac[2*kb+1][2]*rs) | ((u32)f2bf(sac[2*kb+1][3]*rs) << 16);
      af[kb] = cv.v;
    }
    __syncthreads();   // bar2: kwL reads done; chunk commits visible

    // ---- P2b: enc2 = enc_rows @ Wvo; 8 chunks, 2-deep reg prefetch ----
    // invariant @kt: buf[kt&1]=chunk kt; pf[(kt+1)&1]=chunk kt+1 (uncommitted)
    // issue chunk (kt+2)&7 -> pf[kt&1]  (table repeats across jobs)
    f32x4 acc2[16];
    #pragma unroll
    for (int nt = 0; nt < 16; ++nt) acc2[nt] = (f32x4)0.f;
    #pragma unroll
    for (int kt = 0; kt < 8; ++kt) {
      {
        const f32x4* src = wv + ((kt + 2) & 7)*1024;
        if ((kt & 1) == 0) {
          #pragma unroll
          for (int i = 0; i < 3; ++i) { const int idx = tid + 384*i; if (idx < 1024) pf0[i] = src[idx]; }
        } else {
          #pragma unroll
          for (int i = 0; i < 3; ++i) { const int idx = tid + 384*i; if (idx < 1024) pf1[i] = src[idx]; }
        }
      }
      union { u32 u[4]; short8 v; } cv;
      cv.u[0] = (u32)f2bf(evr[kt & 3][0].x) | ((u32)f2bf(evr[kt & 3][0].y) << 16);
      cv.u[1] = (u32)f2bf(evr[kt & 3][0].z) | ((u32)f2bf(evr[kt & 3][0].w) << 16);
      cv.u[2] = (u32)f2bf(evr[kt & 3][1].x) | ((u32)f2bf(evr[kt & 3][1].y) << 16);
      cv.u[3] = (u32)f2bf(evr[kt & 3][1].z) | ((u32)f2bf(evr[kt & 3][1].w) << 16);
      const short8 a = cv.v;
      if (kt < 4) {   // reload ring slot with this job's rows 4..7
        evr[kt & 3][0] = *(const float4*)(ep + 32*(kt + 4));
        evr[kt & 3][1] = *(const float4*)(ep + 32*(kt + 4) + 4);
      }
      const char* buf = wvoD + (kt & 1)*16384;
      #pragma unroll
      for (int nt = 0; nt < 16; ++nt) {
        const short8 bf = *(const short8*)(buf + ((nt*64 + lane) << 4));
        acc2[nt] = __builtin_amdgcn_mfma_f32_16x16x32_bf16(a, bf, acc2[nt], 0, 0, 0);
      }
      if (kt < 7) {   // commit chunk kt+1 -> buf[(kt+1)&1]
        f32x4* bw = (f32x4*)(wvoD + ((kt + 1) & 1)*16384);
        if (((kt + 1) & 1) == 0) {
          #pragma unroll
          for (int i = 0; i < 3; ++i) { const int idx = tid + 384*i; if (idx < 1024) bw[idx] = pf0[i]; }
        } else {
          #pragma unroll
          for (int i = 0; i < 3; ++i) { const int idx = tid + 384*i; if (idx < 1024) bw[idx] = pf1[i]; }
        }
      }
      __syncthreads();
    }

    // ---- P5: commit next-job chunk0 -> buf0 (issued kt=6; readers kt=6 done)
    {
      f32x4* b0 = (f32x4*)wvoD;
      #pragma unroll
      for (int i = 0; i < 3; ++i) { const int idx = tid + 384*i; if (idx < 1024) b0[idx] = pf0[i]; }
    }
    // acc2 -> sigma B-frags (full 16 nt, dedicated fragL)
    const int kb0 = wave >> 1, hi = wave & 1;
    #pragma unroll
    for (int nt = 0; nt < 16; ++nt) {
      uint2 o;
      const f32x4 v = acc2[nt];
      o.x = (u32)f2bf(v[0]) | ((u32)f2bf(v[1]) << 16);
      o.y = (u32)f2bf(v[2]) | ((u32)f2bf(v[3]) << 16);
      *(uint2*)(fragL + (((nt*3 + kb0)*64 + lane) << 4) + hi*8) = o;
    }
    // issue next-job enc ring slots 0..3 (land during P6 and next P1/P2)
    {
      const float* epn = enc + (rowbase + nn)*256 + 8*g;
      #pragma unroll
      for (int kt = 0; kt < 4; ++kt) {
        evr[kt][0] = *(const float4*)(epn + 32*kt);
        evr[kt][1] = *(const float4*)(epn + 32*kt + 4);
      }
      ep = epn;   // in-loop reloads of next job use this
    }
    // commit next-job chunk1 -> buf1 (issued kt=7; readers kt=7 done)
    {
      f32x4* b1 = (f32x4*)(wvoD + 16384);
      #pragma unroll
      for (int i = 0; i < 3; ++i) { const int idx = tid + 384*i; if (idx < 1024) b1[idx] = pf1[i]; }
    }
    __syncthreads();   // bar3: fragL ready

    // ---- P6: out = attn @ enc2 + bvo; f32 store ----
    #pragma unroll
    for (int nt = 0; nt < 16; ++nt) {
      f32x4 oa = (f32x4)0.f;
      #pragma unroll
      for (int kb = 0; kb < 3; ++kb) {
        const short8 ef = *(const short8*)(fragL + (((nt*3 + kb)*64 + lane) << 4));
        oa = __builtin_amdgcn_mfma_f32_16x16x32_bf16(af[kb], ef, oa, 0, 0, 0);
      }
      const int c = c15 + 16*nt;
      const float bz = bvoL[c];
      #pragma unroll
      for (int r = 0; r < 4; ++r) {
        const int qi = 16*wave + 4*g + r;
        out[((size_t)((b*96 + qi)*1024 + n))*256 + c] = oa[r] + bz;
      }
    }
  }
}

// ---------------------------------------------------------------------------
extern "C" void kernel_launch(void* const* d_in, const int* in_sizes, int n_in,
                              void* d_out, int out_size, void* d_ws, size_t ws_size,
                              hipStream_t stream) {
  const float* enc     = (const float*)d_in[0];
  const float* ste_enc = (const float*)d_in[1];
  const float* ste_dec = (const float*)d_in[2];
  const float* Wq = (const float*)d_in[3];
  const float* bq = (const float*)d_in[4];
  const float* Wk = (const float*)d_in[5];
  const float* Wv = (const float*)d_in[7];
  const float* bv = (const float*)d_in[8];
  const float* Wo = (const float*)d_in[9];
  const float* bo = (const float*)d_in[10];
  float* out = (float*)d_out;

  u16*   WkqF = (u16*)d_ws;                               // 36864 B
  u16*   WvoF = (u16*)((char*)d_ws + 36864);              // 131072 B -> 167936
  float* bvo  = (float*)((char*)d_ws + 167936);           // 1024 B

  (void)hipFuncSetAttribute((const void*)k_attn,
        hipFuncAttributeMaxDynamicSharedMemorySize, LDS_TOTAL);

  k_setup<<<dim3(256), dim3(256), 0, stream>>>(Wq, Wk, Wv, Wo, bq, bv, bo,
                                               WkqF, WvoF, bvo);
  k_attn<<<dim3(512), dim3(NTHR), LDS_TOTAL, stream>>>(
      ste_dec, ste_enc, enc, WkqF, WvoF, bvo, out);
}

// Round 13
// 917.739 us; speedup vs baseline: 1.0632x; 1.0632x over previous
//
#include <hip/hip_runtime.h>
#include <stdint.h>

typedef unsigned short u16;
typedef unsigned int u32;
typedef __attribute__((ext_vector_type(8))) short short8;   // 8 bf16 (4 VGPR)
typedef __attribute__((ext_vector_type(4))) float f32x4;

#define NTHR 384
#define JOBS 16
#define K2E16 0.09016844005556021f   /* log2(e)/16 : 1/sqrt(256) folded into exp2 */

// LDS map (158592 B, 1 block/CU):
//   wvoL  [0, 131072)      : FULL Wvo frag table, staged once per block
//   kwL   [131072, 157184) : KW bf16 [96][272B] per job; fragH (24576) overlays
//   biasL f32[96] @157184, bvoL f32[256] @157568  -> total 158592
#define KW_OFF    131072
#define KW_STRIDE 272
#define BIAS_OFF  157184
#define BVO_OFF   157568
#define LDS_TOTAL 158592

static __device__ __forceinline__ u16 f2bf(float f) {
  union { float f; u32 u; } v; v.f = f;
  u32 r = v.u + 0x7FFFu + ((v.u >> 16) & 1u);   // RNE
  return (u16)(r >> 16);
}

// ---------------------------------------------------------------------------
// K0: weight prep (identical to round-10/11 verified version).
//  - WkqE: bf16 B-frags (K=128, 9 col-tiles; col 128 = Wk·bq bias column).
//  - WvoF: bf16 B-frags of Wv@Wo, frag (kt*16+nt) contiguous 1KB each.
//  - bvo = bv@Wo + bo (f32).
// ---------------------------------------------------------------------------
__global__ __launch_bounds__(256) void k_setup(
    const float* __restrict__ Wq, const float* __restrict__ Wk,
    const float* __restrict__ Wv, const float* __restrict__ Wo,
    const float* __restrict__ bq,
    const float* __restrict__ bv, const float* __restrict__ bo,
    u16* __restrict__ WkqF, u16* __restrict__ WvoF, float* __restrict__ bvo) {
  const int ci = blockIdx.x;   // k-row
  const int co = threadIdx.x;  // col
  float acc = 0.f;
  for (int h = 0; h < 256; ++h) acc += Wv[ci*256 + h] * Wo[h*256 + co];
  const int lanepart = ((ci >> 3) & 3)*16 + (co & 15), e = ci & 7;
  const int idxv = (((ci >> 5)*16 + (co >> 4))*64 + lanepart)*8 + e;
  WvoF[idxv] = f2bf(acc);
  if (ci < 128 && co < 144) {
    float a = 0.f;
    if (co < 128)       { for (int h = 0; h < 256; ++h) a += Wk[ci*256 + h] * Wq[co*256 + h]; }
    else if (co == 128) { for (int h = 0; h < 256; ++h) a += Wk[ci*256 + h] * bq[h]; }
    const int idx = (((ci >> 5)*9 + (co >> 4))*64 + lanepart)*8 + e;
    WkqF[idx] = f2bf(a);
  }
  if (ci == 0) {
    float a2 = 0.f;
    for (int h = 0; h < 256; ++h) a2 += bv[h] * Wo[h*256 + co];
    bvo[co] = a2 + bo[co];
  }
}

// ---------------------------------------------------------------------------
// K2 persistent-job kernel, grid (512), 6 waves, 158592B LDS, 1 block/CU.
// Block blk: b = blk>>6, n in [n0, n0+16), n0 = (blk&63)*16.
// Per job (6 barriers):
//   P1: KW = senc_rows@WkqE -> kwL (B direct global, L2-hot); next sd/se issued
//   bar1 | P2: scoresT + softmax + af  | P2b: 128 MFMA vs RESIDENT wvoL,
//   zero barriers; evr ring reloads rows 4..7 then next-job rows 0..3
//   bar2 | P5a fragA | bar3 | P6a PV cols 0..127 | bar4 | P5b fragB | bar5 |
//   P6b PV cols 128..255 | bar6 (loop: fragB reads done before next kwL write)
// ---------------------------------------------------------------------------
__global__ __launch_bounds__(NTHR, 1) void k_attn(
    const float* __restrict__ sdec, const float* __restrict__ senc,
    const float* __restrict__ enc,
    const u16* __restrict__ WkqF, const u16* __restrict__ WvoF,
    const float* __restrict__ bvo, float* __restrict__ out) {
  extern __shared__ char smem[];
  char* wvoL   = smem;
  char* kwL    = smem + KW_OFF;
  char* fragH  = smem + KW_OFF;    // 24576 over kwL (P5..P6)
  float* biasL = (float*)(smem + BIAS_OFF);
  float* bvoL  = (float*)(smem + BVO_OFF);

  const int blk = blockIdx.x;
  const int b = blk >> 6;
  const int n0 = (blk & 63) << 4;
  const int tid = threadIdx.x, wave = tid >> 6, lane = tid & 63;
  const int g = lane >> 4, c15 = lane & 15;
  const int prow = 16*wave + c15;      // this wave's A-fragment row
  const size_t rowbase = (size_t)(b*96 + prow)*1024;

  // ---- prologue: job0 inputs first (P1 critical path), then Wvo staging ----
  const float* sdp = sdec + (rowbase + n0)*128 + 8*g;
  const float* sep = senc + (rowbase + n0)*128 + 8*g;
  float4 sdv[4][2], sev[4][2];
  #pragma unroll
  for (int kt = 0; kt < 4; ++kt) {
    sev[kt][0] = *(const float4*)(sep + 32*kt);
    sev[kt][1] = *(const float4*)(sep + 32*kt + 4);
    sdv[kt][0] = *(const float4*)(sdp + 32*kt);
    sdv[kt][1] = *(const float4*)(sdp + 32*kt + 4);
  }
  const float* ep = enc + (rowbase + n0)*256 + 8*g;
  float4 evr[4][2];
  #pragma unroll
  for (int kt = 0; kt < 4; ++kt) {
    evr[kt][0] = *(const float4*)(ep + 32*kt);
    evr[kt][1] = *(const float4*)(ep + 32*kt + 4);
  }
  if (tid < 256) bvoL[tid] = bvo[tid];

  // stage full Wvo table (8192 f32x4) in two reg batches of 11
  {
    const f32x4* wvg = (const f32x4*)WvoF;
    f32x4* wvl = (f32x4*)wvoL;
    f32x4 t[11];
    #pragma unroll
    for (int i = 0; i < 11; ++i) t[i] = wvg[tid + 384*i];
    #pragma unroll
    for (int i = 0; i < 11; ++i) wvl[tid + 384*i] = t[i];
    #pragma unroll
    for (int i = 0; i < 11; ++i) {
      const int idx = 4224 + tid + 384*i;
      if (idx < 8192) t[i] = wvg[idx];
    }
    #pragma unroll
    for (int i = 0; i < 11; ++i) {
      const int idx = 4224 + tid + 384*i;
      if (idx < 8192) wvl[idx] = t[i];
    }
  }
  __syncthreads();   // bar0: wvoL + bvoL staged

  // ================= job loop =================
  #pragma unroll 1
  for (int j = 0; j < JOBS; ++j) {
    const int n = n0 + j;
    const int nn = n0 + ((j + 1) & (JOBS - 1));   // next job (wraps)

    // convert this job's inputs (loads issued a full job ago)
    short8 sef[4], sdf[4];
    #pragma unroll
    for (int kt = 0; kt < 4; ++kt) {
      union { u32 u[4]; short8 v; } cv;
      cv.u[0] = (u32)f2bf(sev[kt][0].x) | ((u32)f2bf(sev[kt][0].y) << 16);
      cv.u[1] = (u32)f2bf(sev[kt][0].z) | ((u32)f2bf(sev[kt][0].w) << 16);
      cv.u[2] = (u32)f2bf(sev[kt][1].x) | ((u32)f2bf(sev[kt][1].y) << 16);
      cv.u[3] = (u32)f2bf(sev[kt][1].z) | ((u32)f2bf(sev[kt][1].w) << 16);
      sef[kt] = cv.v;
    }
    #pragma unroll
    for (int kt = 0; kt < 4; ++kt) {
      union { u32 u[4]; short8 v; } cv;
      cv.u[0] = (u32)f2bf(sdv[kt][0].x) | ((u32)f2bf(sdv[kt][0].y) << 16);
      cv.u[1] = (u32)f2bf(sdv[kt][0].z) | ((u32)f2bf(sdv[kt][0].w) << 16);
      cv.u[2] = (u32)f2bf(sdv[kt][1].x) | ((u32)f2bf(sdv[kt][1].y) << 16);
      cv.u[3] = (u32)f2bf(sdv[kt][1].z) | ((u32)f2bf(sdv[kt][1].w) << 16);
      sdf[kt] = cv.v;
    }
    // issue NEXT job's sd/se loads (land during this job's compute)
    {
      const float* sdpn = sdec + (rowbase + nn)*128 + 8*g;
      const float* sepn = senc + (rowbase + nn)*128 + 8*g;
      #pragma unroll
      for (int kt = 0; kt < 4; ++kt) {
        sev[kt][0] = *(const float4*)(sepn + 32*kt);
        sev[kt][1] = *(const float4*)(sepn + 32*kt + 4);
        sdv[kt][0] = *(const float4*)(sdpn + 32*kt);
        sdv[kt][1] = *(const float4*)(sdpn + 32*kt + 4);
      }
    }

    // ---- P1: KW rows [16w,16w+16) x 144 = senc_rows @ WkqE (B direct) ----
    {
      f32x4 acc[9];
      #pragma unroll
      for (int nt = 0; nt < 9; ++nt) acc[nt] = (f32x4)0.f;
      #pragma unroll
      for (int kt = 0; kt < 4; ++kt) {
        #pragma unroll
        for (int nt = 0; nt < 9; ++nt) {
          const short8 bf = *(const short8*)(WkqF + (size_t)((kt*9 + nt)*64 + lane)*8);
          acc[nt] = __builtin_amdgcn_mfma_f32_16x16x32_bf16(sef[kt], bf, acc[nt], 0, 0, 0);
        }
      }
      #pragma unroll
      for (int nt = 0; nt < 8; ++nt) {
        #pragma unroll
        for (int r = 0; r < 4; ++r)
          *(u16*)(kwL + (16*wave + 4*g + r)*KW_STRIDE + 2*(c15 + 16*nt)) = f2bf(acc[nt][r]);
      }
      if (c15 == 0) {
        #pragma unroll
        for (int r = 0; r < 4; ++r) biasL[16*wave + 4*g + r] = acc[8][r];
      }
    }
    __syncthreads();   // bar1: kwL + biasL ready

    // ---- P2: scoresT = KW[:,0:128] @ sdecT + bias; softmax; af pack ----
    f32x4 sac[6];
    #pragma unroll
    for (int pt = 0; pt < 6; ++pt) sac[pt] = (f32x4)0.f;
    #pragma unroll
    for (int kt = 0; kt < 4; ++kt) {
      #pragma unroll
      for (int pt = 0; pt < 6; ++pt) {
        const short8 kf = *(const short8*)(kwL + (16*pt + c15)*KW_STRIDE + 16*g + 64*kt);
        sac[pt] = __builtin_amdgcn_mfma_f32_16x16x32_bf16(kf, sdf[kt], sac[pt], 0, 0, 0);
      }
    }
    #pragma unroll
    for (int pt = 0; pt < 6; ++pt)
      #pragma unroll
      for (int r = 0; r < 4; ++r)
        sac[pt][r] += biasL[16*pt + 4*g + r];

    float m = sac[0][0];
    #pragma unroll
    for (int pt = 0; pt < 6; ++pt)
      #pragma unroll
      for (int r = 0; r < 4; ++r) m = fmaxf(m, sac[pt][r]);
    m = fmaxf(m, __shfl_xor(m, 16));
    m = fmaxf(m, __shfl_xor(m, 32));
    float s = 0.f;
    #pragma unroll
    for (int pt = 0; pt < 6; ++pt)
      #pragma unroll
      for (int r = 0; r < 4; ++r) {
        const float e = exp2f((sac[pt][r] - m) * K2E16);
        sac[pt][r] = e; s += e;
      }
    s += __shfl_xor(s, 16);
    s += __shfl_xor(s, 32);
    const float rs = 1.f / s;

    short8 af[3];
    #pragma unroll
    for (int kb = 0; kb < 3; ++kb) {
      union { u32 u[4]; short8 v; } cv;
      cv.u[0] = (u32)f2bf(sac[2*kb][0]*rs)   | ((u32)f2bf(sac[2*kb][1]*rs)   << 16);
      cv.u[1] = (u32)f2bf(sac[2*kb][2]*rs)   | ((u32)f2bf(sac[2*kb][3]*rs)   << 16);
      cv.u[2] = (u32)f2bf(sac[2*kb+1][0]*rs) | ((u32)f2bf(sac[2*kb+1][1]*rs) << 16);
      cv.u[3] = (u32)f2bf(sac[2*kb+1][2]*rs) | ((u32)f2bf(sac[2*kb+1][3]*rs) << 16);
      af[kb] = cv.v;
    }

    // ---- P2b: enc2 = enc_rows @ Wvo; RESIDENT wvoL, no barriers ----
    // evr ring: kt<4 consumes rows kt, reloads rows kt+4 (this job);
    //           kt>=4 consumes rows kt, reloads next job's rows kt-4.
    f32x4 acc2[16];
    #pragma unroll
    for (int nt = 0; nt < 16; ++nt) acc2[nt] = (f32x4)0.f;
    const float* epn = enc + (rowbase + nn)*256 + 8*g;
    #pragma unroll
    for (int kt = 0; kt < 8; ++kt) {
      union { u32 u[4]; short8 v; } cv;
      cv.u[0] = (u32)f2bf(evr[kt & 3][0].x) | ((u32)f2bf(evr[kt & 3][0].y) << 16);
      cv.u[1] = (u32)f2bf(evr[kt & 3][0].z) | ((u32)f2bf(evr[kt & 3][0].w) << 16);
      cv.u[2] = (u32)f2bf(evr[kt & 3][1].x) | ((u32)f2bf(evr[kt & 3][1].y) << 16);
      cv.u[3] = (u32)f2bf(evr[kt & 3][1].z) | ((u32)f2bf(evr[kt & 3][1].w) << 16);
      const short8 a = cv.v;
      if (kt < 4) {
        evr[kt & 3][0] = *(const float4*)(ep + 32*(kt + 4));
        evr[kt & 3][1] = *(const float4*)(ep + 32*(kt + 4) + 4);
      } else {
        evr[kt & 3][0] = *(const float4*)(epn + 32*(kt - 4));
        evr[kt & 3][1] = *(const float4*)(epn + 32*(kt - 4) + 4);
      }
      #pragma unroll
      for (int nt = 0; nt < 16; ++nt) {
        const short8 bf = *(const short8*)(wvoL + (((kt*16 + nt)*64 + lane) << 4));
        acc2[nt] = __builtin_amdgcn_mfma_f32_16x16x32_bf16(a, bf, acc2[nt], 0, 0, 0);
      }
    }
    ep = epn;
    __syncthreads();   // bar2: kwL reads (P2) done -> fragH writable

    // ---- P5/P6: sigma frag exchange + PV + store, two col-halves ----
    const int kb0 = wave >> 1, hi = wave & 1;
    #pragma unroll
    for (int half = 0; half < 2; ++half) {
      #pragma unroll
      for (int ntl = 0; ntl < 8; ++ntl) {
        uint2 o;
        const f32x4 v = acc2[half*8 + ntl];
        o.x = (u32)f2bf(v[0]) | ((u32)f2bf(v[1]) << 16);
        o.y = (u32)f2bf(v[2]) | ((u32)f2bf(v[3]) << 16);
        *(uint2*)(fragH + (((ntl*3 + kb0)*64 + lane) << 4) + hi*8) = o;
      }
      __syncthreads();   // bar3/bar5: frag half ready
      #pragma unroll
      for (int ntl = 0; ntl < 8; ++ntl) {
        f32x4 oa = (f32x4)0.f;
        #pragma unroll
        for (int kb = 0; kb < 3; ++kb) {
          const short8 ef = *(const short8*)(fragH + (((ntl*3 + kb)*64 + lane) << 4));
          oa = __builtin_amdgcn_mfma_f32_16x16x32_bf16(af[kb], ef, oa, 0, 0, 0);
        }
        const int c = c15 + 16*(half*8 + ntl);
        const float bz = bvoL[c];
        #pragma unroll
        for (int r = 0; r < 4; ++r) {
          const int qi = 16*wave + 4*g + r;
          out[((size_t)((b*96 + qi)*1024 + n))*256 + c] = oa[r] + bz;
        }
      }
      __syncthreads();   // bar4/bar6: frag reads done (next half / next job P1)
    }
  }
}

// ---------------------------------------------------------------------------
extern "C" void kernel_launch(void* const* d_in, const int* in_sizes, int n_in,
                              void* d_out, int out_size, void* d_ws, size_t ws_size,
                              hipStream_t stream) {
  const float* enc     = (const float*)d_in[0];
  const float* ste_enc = (const float*)d_in[1];
  const float* ste_dec = (const float*)d_in[2];
  const float* Wq = (const float*)d_in[3];
  const float* bq = (const float*)d_in[4];
  const float* Wk = (const float*)d_in[5];
  const float* Wv = (const float*)d_in[7];
  const float* bv = (const float*)d_in[8];
  const float* Wo = (const float*)d_in[9];
  const float* bo = (const float*)d_in[10];
  float* out = (float*)d_out;

  u16*   WkqF = (u16*)d_ws;                               // 36864 B
  u16*   WvoF = (u16*)((char*)d_ws + 36864);              // 131072 B -> 167936
  float* bvo  = (float*)((char*)d_ws + 167936);           // 1024 B

  (void)hipFuncSetAttribute((const void*)k_attn,
        hipFuncAttributeMaxDynamicSharedMemorySize, LDS_TOTAL);

  k_setup<<<dim3(256), dim3(256), 0, stream>>>(Wq, Wk, Wv, Wo, bq, bv, bo,
                                               WkqF, WvoF, bvo);
  k_attn<<<dim3(512), dim3(NTHR), LDS_TOTAL, stream>>>(
      ste_dec, ste_enc, enc, WkqF, WvoF, bvo, out);
}

// Round 15
// 588.489 us; speedup vs baseline: 1.6580x; 1.5595x over previous
//
#include <hip/hip_runtime.h>
#include <stdint.h>

typedef unsigned short u16;
typedef unsigned int u32;
typedef __attribute__((ext_vector_type(8))) short short8;   // 8 bf16 (4 VGPR)
typedef __attribute__((ext_vector_type(4))) float f32x4;

#define NTHR 384
#define K2E16 0.09016844005556021f   /* log2(e)/16 : 1/sqrt(256) folded into exp2 */

// LDS map (93056 B, 1 block/CU by design):
//   wvoD  [0, 65536)     : Wkq compact 32KB (P0..P1) -> Wvo 32KB dbuf (P2b)
//                          -> fragB 24576 (P5..P6)
//   kwL   [65536, 91648) : KW bf16 [96][272B] (P1..P2) -> fragA 24576
//   biasL f32[96] @91648, bvoL f32[256] @92032 -> total 93056
#define KW_OFF    65536
#define KW_STRIDE 272
#define BIAS_OFF  91648
#define BVO_OFF   92032
#define LDS_TOTAL 93056

static __device__ __forceinline__ u16 f2bf(float f) {
  union { float f; u32 u; } v; v.f = f;
  u32 r = v.u + 0x7FFFu + ((v.u >> 16) & 1u);   // RNE
  return (u16)(r >> 16);
}

// ---------------------------------------------------------------------------
// K0: weight prep (identical to round-10/11 verified version).
//  - WkqE: bf16 B-frags (K=128, 9 col-tiles; col 128 = Wk·bq bias column).
//  - WvoF: bf16 B-frags of Wv@Wo, frag (kt*16+nt) contiguous 1KB each.
//  - bvo = bv@Wo + bo (f32).
// ---------------------------------------------------------------------------
__global__ __launch_bounds__(256) void k_setup(
    const float* __restrict__ Wq, const float* __restrict__ Wk,
    const float* __restrict__ Wv, const float* __restrict__ Wo,
    const float* __restrict__ bq,
    const float* __restrict__ bv, const float* __restrict__ bo,
    u16* __restrict__ WkqF, u16* __restrict__ WvoF, float* __restrict__ bvo) {
  const int ci = blockIdx.x;   // k-row
  const int co = threadIdx.x;  // col
  float acc = 0.f;
  for (int h = 0; h < 256; ++h) acc += Wv[ci*256 + h] * Wo[h*256 + co];
  const int lanepart = ((ci >> 3) & 3)*16 + (co & 15), e = ci & 7;
  const int idxv = (((ci >> 5)*16 + (co >> 4))*64 + lanepart)*8 + e;
  WvoF[idxv] = f2bf(acc);
  if (ci < 128 && co < 144) {
    float a = 0.f;
    if (co < 128)       { for (int h = 0; h < 256; ++h) a += Wk[ci*256 + h] * Wq[co*256 + h]; }
    else if (co == 128) { for (int h = 0; h < 256; ++h) a += Wk[ci*256 + h] * bq[h]; }
    const int idx = (((ci >> 5)*9 + (co >> 4))*64 + lanepart)*8 + e;
    WkqF[idx] = f2bf(a);
  }
  if (ci == 0) {
    float a2 = 0.f;
    for (int h = 0; h < 256; ++h) a2 += bv[h] * Wo[h*256 + co];
    bvo[co] = a2 + bo[co];
  }
}

// ---------------------------------------------------------------------------
// K2 fused, grid (1024, 8), 6 waves, 93056B LDS, 1 block/CU (by design).
//   P0: issue Wkq-stage loads (32KB->wvoD), sd/se loads, Wvo chunk0 (32KB), bvo
//   P1: KW = senc_rows@WkqE -> kwL; B-frags nt0-7 from LDS, nt8 direct
//   bar1 -> commit chunk0; issue chunk1; preload enc ring; P2 scores+softmax
//   bar2 -> P2b: 4 x 32KB chunks, reg-prefetch 2 deep, 4 in-loop barriers
//   P5: acc2 -> sigma B-frags (fragA over kwL, fragB over wvoD.buf0), one sync
//   P6: out = attn@enc2 + bvo
// bf16 packing: verified manual-RNE f2bf (r14's cvt_pk asm produced NaN).
// ---------------------------------------------------------------------------
__global__ __launch_bounds__(NTHR, 2) void k_attn(
    const float* __restrict__ sdec, const float* __restrict__ senc,
    const float* __restrict__ enc,
    const u16* __restrict__ WkqF, const u16* __restrict__ WvoF,
    const float* __restrict__ bvo, float* __restrict__ out) {
  extern __shared__ char smem[];
  char* wvoD   = smem;             // Wkq stage -> Wvo dbuf -> fragB
  char* kwL    = smem + KW_OFF;
  char* fragA  = smem + KW_OFF;
  char* fragB  = smem;
  float* biasL = (float*)(smem + BIAS_OFF);
  float* bvoL  = (float*)(smem + BVO_OFF);

  const int n = blockIdx.x, b = blockIdx.y;
  const int tid = threadIdx.x, wave = tid >> 6, lane = tid & 63;
  const int g = lane >> 4, c15 = lane & 15;
  const int prow = 16*wave + c15;      // this wave's A-fragment row

  // ---- P0: issue Wkq stage loads FIRST (oldest -> earliest waitable) ----
  f32x4 wkq[6];
  #pragma unroll
  for (int i = 0; i < 6; ++i) {
    const int idx = tid + 384*i;
    if (idx < 2048) {
      const int f = idx >> 6, l = idx & 63;          // frag 0..31 (kt,nt<8)
      wkq[i] = ((const f32x4*)WkqF)[((f >> 3)*9 + (f & 7))*64 + l];
    }
  }
  // sd/se fragment loads (wave-own rows)
  const float* sdp = sdec + ((size_t)((b*96 + prow)*1024 + n))*128 + 8*g;
  const float* sep = senc + ((size_t)((b*96 + prow)*1024 + n))*128 + 8*g;
  float4 sdv[4][2], sev[4][2];
  #pragma unroll
  for (int kt = 0; kt < 4; ++kt) {
    sev[kt][0] = *(const float4*)(sep + 32*kt);
    sev[kt][1] = *(const float4*)(sep + 32*kt + 4);
    sdv[kt][0] = *(const float4*)(sdp + 32*kt);
    sdv[kt][1] = *(const float4*)(sdp + 32*kt + 4);
  }
  const f32x4* wv = (const f32x4*)WvoF;   // 32KB chunk c = wv + c*2048
  f32x4 c0[6];
  #pragma unroll
  for (int i = 0; i < 6; ++i) {
    const int idx = tid + 384*i;
    if (idx < 2048) c0[i] = wv[idx];
  }
  if (tid < 256) bvoL[tid] = bvo[tid];

  // commit Wkq -> wvoD (waits only its own 6 loads; sd/se/c0 keep flying)
  {
    f32x4* d = (f32x4*)wvoD;
    #pragma unroll
    for (int i = 0; i < 6; ++i) {
      const int idx = tid + 384*i;
      if (idx < 2048) d[idx] = wkq[i];
    }
  }
  __syncthreads();   // bar0: Wkq staged

  short8 sef[4], sdf[4];
  #pragma unroll
  for (int kt = 0; kt < 4; ++kt) {
    union { u32 u[4]; short8 v; } cv;
    cv.u[0] = (u32)f2bf(sev[kt][0].x) | ((u32)f2bf(sev[kt][0].y) << 16);
    cv.u[1] = (u32)f2bf(sev[kt][0].z) | ((u32)f2bf(sev[kt][0].w) << 16);
    cv.u[2] = (u32)f2bf(sev[kt][1].x) | ((u32)f2bf(sev[kt][1].y) << 16);
    cv.u[3] = (u32)f2bf(sev[kt][1].z) | ((u32)f2bf(sev[kt][1].w) << 16);
    sef[kt] = cv.v;
  }
  #pragma unroll
  for (int kt = 0; kt < 4; ++kt) {
    union { u32 u[4]; short8 v; } cv;
    cv.u[0] = (u32)f2bf(sdv[kt][0].x) | ((u32)f2bf(sdv[kt][0].y) << 16);
    cv.u[1] = (u32)f2bf(sdv[kt][0].z) | ((u32)f2bf(sdv[kt][0].w) << 16);
    cv.u[2] = (u32)f2bf(sdv[kt][1].x) | ((u32)f2bf(sdv[kt][1].y) << 16);
    cv.u[3] = (u32)f2bf(sdv[kt][1].z) | ((u32)f2bf(sdv[kt][1].w) << 16);
    sdf[kt] = cv.v;
  }

  // ---- P1: KW rows [16w,16w+16) x 144 = senc_rows @ WkqE ----
  {
    f32x4 acc[9];
    #pragma unroll
    for (int nt = 0; nt < 9; ++nt) acc[nt] = (f32x4)0.f;
    #pragma unroll
    for (int kt = 0; kt < 4; ++kt) {
      #pragma unroll
      for (int nt = 0; nt < 8; ++nt) {
        const short8 bf = *(const short8*)(wvoD + ((kt*8 + nt)*64 + lane)*16);
        acc[nt] = __builtin_amdgcn_mfma_f32_16x16x32_bf16(sef[kt], bf, acc[nt], 0, 0, 0);
      }
      const short8 bf8 = *(const short8*)(WkqF + (size_t)((kt*9 + 8)*64 + lane)*8);
      acc[8] = __builtin_amdgcn_mfma_f32_16x16x32_bf16(sef[kt], bf8, acc[8], 0, 0, 0);
    }
    #pragma unroll
    for (int nt = 0; nt < 8; ++nt) {
      #pragma unroll
      for (int r = 0; r < 4; ++r)
        *(u16*)(kwL + (16*wave + 4*g + r)*KW_STRIDE + 2*(c15 + 16*nt)) = f2bf(acc[nt][r]);
    }
    if (c15 == 0) {
      #pragma unroll
      for (int r = 0; r < 4; ++r) biasL[16*wave + 4*g + r] = acc[8][r];
    }
  }
  __syncthreads();   // bar1: kwL + biasL ready; wvoD (Wkq) reads done

  // ---- commit chunk0 -> buf0; issue chunk1 -> pf0 (lands during P2) ----
  {
    f32x4* b0 = (f32x4*)wvoD;
    #pragma unroll
    for (int i = 0; i < 6; ++i) {
      const int idx = tid + 384*i;
      if (idx < 2048) b0[idx] = c0[i];
    }
  }
  f32x4 pf0[6], pf1[6];
  #pragma unroll
  for (int i = 0; i < 6; ++i) {
    const int idx = tid + 384*i;
    if (idx < 2048) pf0[i] = wv[2048 + idx];
  }
  // preload enc ring slots 0..3 (land during P2)
  const float* ep = enc + ((size_t)((b*96 + prow)*1024 + n))*256 + 8*g;
  float4 evr[4][2];
  #pragma unroll
  for (int kt = 0; kt < 4; ++kt) {
    evr[kt][0] = *(const float4*)(ep + 32*kt);
    evr[kt][1] = *(const float4*)(ep + 32*kt + 4);
  }

  // ---- P2: scoresT = KW[:,0:128] @ sdecT + bias; softmax; af pack ----
  f32x4 sac[6];
  #pragma unroll
  for (int pt = 0; pt < 6; ++pt) sac[pt] = (f32x4)0.f;
  #pragma unroll
  for (int kt = 0; kt < 4; ++kt) {
    #pragma unroll
    for (int pt = 0; pt < 6; ++pt) {
      const short8 kf = *(const short8*)(kwL + (16*pt + c15)*KW_STRIDE + 16*g + 64*kt);
      sac[pt] = __builtin_amdgcn_mfma_f32_16x16x32_bf16(kf, sdf[kt], sac[pt], 0, 0, 0);
    }
  }
  #pragma unroll
  for (int pt = 0; pt < 6; ++pt)
    #pragma unroll
    for (int r = 0; r < 4; ++r)
      sac[pt][r] += biasL[16*pt + 4*g + r];

  float m = sac[0][0];
  #pragma unroll
  for (int pt = 0; pt < 6; ++pt)
    #pragma unroll
    for (int r = 0; r < 4; ++r) m = fmaxf(m, sac[pt][r]);
  m = fmaxf(m, __shfl_xor(m, 16));
  m = fmaxf(m, __shfl_xor(m, 32));
  float s = 0.f;
  #pragma unroll
  for (int pt = 0; pt < 6; ++pt)
    #pragma unroll
    for (int r = 0; r < 4; ++r) {
      const float e = exp2f((sac[pt][r] - m) * K2E16);
      sac[pt][r] = e; s += e;
    }
  s += __shfl_xor(s, 16);
  s += __shfl_xor(s, 32);
  const float rs = 1.f / s;

  short8 af[3];
  #pragma unroll
  for (int kb = 0; kb < 3; ++kb) {
    union { u32 u[4]; short8 v; } cv;
    cv.u[0] = (u32)f2bf(sac[2*kb][0]*rs)   | ((u32)f2bf(sac[2*kb][1]*rs)   << 16);
    cv.u[1] = (u32)f2bf(sac[2*kb][2]*rs)   | ((u32)f2bf(sac[2*kb][3]*rs)   << 16);
    cv.u[2] = (u32)f2bf(sac[2*kb+1][0]*rs) | ((u32)f2bf(sac[2*kb+1][1]*rs) << 16);
    cv.u[3] = (u32)f2bf(sac[2*kb+1][2]*rs) | ((u32)f2bf(sac[2*kb+1][3]*rs) << 16);
    af[kb] = cv.v;
  }
  __syncthreads();   // bar2: chunk0 visible; kwL reads (P2) done

  // ---- P2b: enc2 = enc_rows @ Wvo; 4 x 32KB chunks, 2-deep prefetch ----
  // invariant @c: buf[c&1] = chunk c; commit chunk c+1 at iter c; issue c+2.
  f32x4 acc2[16];
  #pragma unroll
  for (int nt = 0; nt < 16; ++nt) acc2[nt] = (f32x4)0.f;
  #pragma unroll
  for (int c = 0; c < 4; ++c) {
    if (c < 2) {   // issue chunk c+2
      const f32x4* src = wv + (c + 2)*2048;
      if (c == 0) {
        #pragma unroll
        for (int i = 0; i < 6; ++i) { const int idx = tid + 384*i; if (idx < 2048) pf1[i] = src[idx]; }
      } else {
        #pragma unroll
        for (int i = 0; i < 6; ++i) { const int idx = tid + 384*i; if (idx < 2048) pf0[i] = src[idx]; }
      }
    }
    // convert this chunk's two enc A-frags (slots 2c&3, (2c+1)&3)
    union { u32 u[4]; short8 v; } cva, cvb;
    cva.u[0] = (u32)f2bf(evr[(2*c) & 3][0].x) | ((u32)f2bf(evr[(2*c) & 3][0].y) << 16);
    cva.u[1] = (u32)f2bf(evr[(2*c) & 3][0].z) | ((u32)f2bf(evr[(2*c) & 3][0].w) << 16);
    cva.u[2] = (u32)f2bf(evr[(2*c) & 3][1].x) | ((u32)f2bf(evr[(2*c) & 3][1].y) << 16);
    cva.u[3] = (u32)f2bf(evr[(2*c) & 3][1].z) | ((u32)f2bf(evr[(2*c) & 3][1].w) << 16);
    cvb.u[0] = (u32)f2bf(evr[(2*c+1) & 3][0].x) | ((u32)f2bf(evr[(2*c+1) & 3][0].y) << 16);
    cvb.u[1] = (u32)f2bf(evr[(2*c+1) & 3][0].z) | ((u32)f2bf(evr[(2*c+1) & 3][0].w) << 16);
    cvb.u[2] = (u32)f2bf(evr[(2*c+1) & 3][1].x) | ((u32)f2bf(evr[(2*c+1) & 3][1].y) << 16);
    cvb.u[3] = (u32)f2bf(evr[(2*c+1) & 3][1].z) | ((u32)f2bf(evr[(2*c+1) & 3][1].w) << 16);
    const short8 a0 = cva.v, a1 = cvb.v;
    if (c == 0) {   // reload consumed slots with rows kt=4,5
      evr[0][0] = *(const float4*)(ep + 32*4);  evr[0][1] = *(const float4*)(ep + 32*4 + 4);
      evr[1][0] = *(const float4*)(ep + 32*5);  evr[1][1] = *(const float4*)(ep + 32*5 + 4);
    }
    if (c == 1) {   // reload consumed slots with rows kt=6,7
      evr[2][0] = *(const float4*)(ep + 32*6);  evr[2][1] = *(const float4*)(ep + 32*6 + 4);
      evr[3][0] = *(const float4*)(ep + 32*7);  evr[3][1] = *(const float4*)(ep + 32*7 + 4);
    }
    const char* buf = wvoD + (c & 1)*32768;
    #pragma unroll
    for (int nt = 0; nt < 16; ++nt) {
      const short8 bf = *(const short8*)(buf + ((nt*64 + lane) << 4));
      acc2[nt] = __builtin_amdgcn_mfma_f32_16x16x32_bf16(a0, bf, acc2[nt], 0, 0, 0);
    }
    #pragma unroll
    for (int nt = 0; nt < 16; ++nt) {
      const short8 bf = *(const short8*)(buf + (((16 + nt)*64 + lane) << 4));
      acc2[nt] = __builtin_amdgcn_mfma_f32_16x16x32_bf16(a1, bf, acc2[nt], 0, 0, 0);
    }
    if (c < 3) {   // commit chunk c+1 -> buf[(c+1)&1]
      f32x4* bw = (f32x4*)(wvoD + ((c + 1) & 1)*32768);
      if ((c & 1) == 0) {
        #pragma unroll
        for (int i = 0; i < 6; ++i) { const int idx = tid + 384*i; if (idx < 2048) bw[idx] = pf0[i]; }
      } else {
        #pragma unroll
        for (int i = 0; i < 6; ++i) { const int idx = tid + 384*i; if (idx < 2048) bw[idx] = pf1[i]; }
      }
    }
    __syncthreads();   // 4 in-loop barriers (c=3's also guards fragB overlay)
  }

  // ---- P5: acc2 -> sigma B-frags; fragA (nt 0..7) + fragB (nt 8..15) ----
  const int kb0 = wave >> 1, hi = wave & 1;
  #pragma unroll
  for (int ntl = 0; ntl < 8; ++ntl) {
    uint2 oA, oB;
    const f32x4 vA = acc2[ntl], vB = acc2[8 + ntl];
    oA.x = (u32)f2bf(vA[0]) | ((u32)f2bf(vA[1]) << 16);
    oA.y = (u32)f2bf(vA[2]) | ((u32)f2bf(vA[3]) << 16);
    oB.x = (u32)f2bf(vB[0]) | ((u32)f2bf(vB[1]) << 16);
    oB.y = (u32)f2bf(vB[2]) | ((u32)f2bf(vB[3]) << 16);
    *(uint2*)(fragA + (((ntl*3 + kb0)*64 + lane) << 4) + hi*8) = oA;
    *(uint2*)(fragB + (((ntl*3 + kb0)*64 + lane) << 4) + hi*8) = oB;
  }
  __syncthreads();   // frags ready

  // ---- P6: out = attn @ enc2 + bvo; f32 store ----
  #pragma unroll
  for (int nt = 0; nt < 16; ++nt) {
    const char* fb = (nt < 8) ? fragA : fragB;
    const int ntl = nt & 7;
    f32x4 oa = (f32x4)0.f;
    #pragma unroll
    for (int kb = 0; kb < 3; ++kb) {
      const short8 ef = *(const short8*)(fb + (((ntl*3 + kb)*64 + lane) << 4));
      oa = __builtin_amdgcn_mfma_f32_16x16x32_bf16(af[kb], ef, oa, 0, 0, 0);
    }
    const int c = c15 + 16*nt;
    const float bz = bvoL[c];
    #pragma unroll
    for (int r = 0; r < 4; ++r) {
      const int qi = 16*wave + 4*g + r;
      out[((size_t)((b*96 + qi)*1024 + n))*256 + c] = oa[r] + bz;
    }
  }
}

// ---------------------------------------------------------------------------
extern "C" void kernel_launch(void* const* d_in, const int* in_sizes, int n_in,
                              void* d_out, int out_size, void* d_ws, size_t ws_size,
                              hipStream_t stream) {
  const float* enc     = (const float*)d_in[0];
  const float* ste_enc = (const float*)d_in[1];
  const float* ste_dec = (const float*)d_in[2];
  const float* Wq = (const float*)d_in[3];
  const float* bq = (const float*)d_in[4];
  const float* Wk = (const float*)d_in[5];
  const float* Wv = (const float*)d_in[7];
  const float* bv = (const float*)d_in[8];
  const float* Wo = (const float*)d_in[9];
  const float* bo = (const float*)d_in[10];
  float* out = (float*)d_out;

  u16*   WkqF = (u16*)d_ws;                               // 36864 B
  u16*   WvoF = (u16*)((char*)d_ws + 36864);              // 131072 B -> 167936
  float* bvo  = (float*)((char*)d_ws + 167936);           // 1024 B

  (void)hipFuncSetAttribute((const void*)k_attn,
        hipFuncAttributeMaxDynamicSharedMemorySize, LDS_TOTAL);

  k_setup<<<dim3(256), dim3(256), 0, stream>>>(Wq, Wk, Wv, Wo, bq, bv, bo,
                                               WkqF, WvoF, bvo);
  k_attn<<<dim3(1024, 8), dim3(NTHR), LDS_TOTAL, stream>>>(
      ste_dec, ste_enc, enc, WkqF, WvoF, bvo, out);
}